// Round 4
// baseline (277.965 us; speedup 1.0000x reference)
//
#include <hip/hip_runtime.h>
#include <stdint.h>

constexpr int B = 4, L = 2048, H = 8, D = 64, S = 40, U = 40;
constexpr int HD = H * D;        // 512
constexpr int NC = 64;           // cumsum chunks per b
constexpr int CL = L / NC;       // 32
constexpr int NBLK = 256;
constexpr int MAGIC = 1 << 30;
constexpr int SLOTS = 16;        // int stride between barrier slots (64 B anti-contention pad)

// monotone float->uint mapping: larger float => larger uint
__device__ __forceinline__ unsigned mono(float v) {
    unsigned u = __float_as_uint(v);
    return (u & 0x80000000u) ? ~u : (u | 0x80000000u);
}

// Device-scope grid barrier. Slot init value is whatever the harness poison
// left (0xAAAAAAAA < MAGIC as signed int; zeros also < MAGIC), so a signed
// >= MAGIC+phase test needs no initialization. All 256 blocks are co-resident
// (256 blocks on 256 CUs, each block needs only 8 waves + ~50 KB LDS), so
// spinning cannot deadlock.
__device__ __forceinline__ void grid_barrier(int* slots, int bid, int phase) {
    __syncthreads();
    __threadfence();                       // release: make prior writes device-visible
    if (threadIdx.x == 0)
        atomicExch(&slots[bid * SLOTS], MAGIC + phase);
    if (threadIdx.x < NBLK) {
        while (atomicAdd(&slots[threadIdx.x * SLOTS], 0) < MAGIC + phase)
            __builtin_amdgcn_s_sleep(8);
    }
    __threadfence();                       // acquire: invalidate stale caches
    __syncthreads();
}

__global__ __launch_bounds__(512) void k_fused(
    const float4* __restrict__ Q4, const float4* __restrict__ K4,
    const float* __restrict__ V, const int* __restrict__ idxs,
    float* __restrict__ Mg, int* __restrict__ flags, float* __restrict__ upd,
    float* __restrict__ partial, int* __restrict__ slots, float* __restrict__ out)
{
    __shared__ float4 Ms4[512];                    // M row of one bh (2048 floats)
    __shared__ unsigned long long cnd[8 * U];      // 320 candidates
    __shared__ int top_idx[U];
    __shared__ __align__(16) float Qs[U * 68];
    __shared__ __align__(16) float Ks[U * 68];
    __shared__ __align__(16) float Vs[U * 68];
    __shared__ float P[U * 41];

    int bid = blockIdx.x;
    int tid = threadIdx.x;
    // XCD swizzle: blocks land on XCD bid%8; pin each b to an XCD pair so its
    // 4 MB K slab stays L2-resident for the phase-A gather.
    int b   = (bid & 7) >> 1;
    int sub = ((bid >> 3) << 1) | (bid & 1);       // 0..63 within b
    int c   = sub;                                  // this block's cumsum chunk

    // ---------------- Phase A: M scores + V chunk sums + flag zeroing -------
    {
        int w = tid >> 6, lane = tid & 63;
        int dd = lane & 7;
        for (int j = 0; j < 4; ++j) {
            int q = sub * 32 + w * 4 + j;
            const float4* qrow = Q4 + (size_t)(b * L + q) * 128;
            float4 qa = qrow[2 * lane], qb = qrow[2 * lane + 1];
            int v_idx = idxs[q * S + (lane < S ? lane : 0)];
            float mx = -INFINITY, sm = 0.f;
            #pragma unroll 8
            for (int s = 0; s < S; ++s) {
                int ki = __shfl(v_idx, s);
                const float4* krow = K4 + (size_t)(b * L + ki) * 128;
                float4 ka = krow[2 * lane], kb = krow[2 * lane + 1];
                float dt = qa.x * ka.x + qa.y * ka.y + qa.z * ka.z + qa.w * ka.w
                         + qb.x * kb.x + qb.y * kb.y + qb.z * kb.z + qb.w * kb.w;
                dt += __shfl_xor(dt, 1);
                dt += __shfl_xor(dt, 2);
                dt += __shfl_xor(dt, 4);
                mx = fmaxf(mx, dt);
                sm += dt;
            }
            if (dd == 0) {
                int h = lane >> 3;
                Mg[(size_t)(b * 8 + h) * L + q] = mx - sm * (1.0f / (float)L);
            }
        }
    }
    {   // V chunk sum for (b, c)
        const float* vp = V + ((size_t)(b * L + c * CL)) * HD + tid;
        float s = 0.f;
        #pragma unroll
        for (int l = 0; l < CL; ++l) s += vp[(size_t)l * HD];
        partial[((size_t)b * NC + c) * HD + tid] = s;
    }
    if (tid < 256) {   // zero flags for this chunk's rows, all 8 heads
        int h = tid >> 5, l0 = c * CL + (tid & 31);
        flags[(size_t)(b * 8 + h) * L + l0] = 0;
    }

    grid_barrier(slots, bid, 1);

    // ---------------- Phase B: selection + attention (32 blocks) ------------
    if (sub < 8) {
        int h = sub, bh = b * 8 + h;
        Ms4[tid] = ((const float4*)(Mg + (size_t)bh * L))[tid];
        __syncthreads();

        // per-segment (8 x 256) exact rank counting, one wave per segment
        {
            int w = tid >> 6, lane = tid & 63;
            float4 v = Ms4[w * 64 + lane];
            unsigned m[4] = { mono(v.x), mono(v.y), mono(v.z), mono(v.w) };
            int rank[4] = { 0, 0, 0, 0 };
            #pragma unroll 4
            for (int src = 0; src < 64; ++src) {
                #pragma unroll
                for (int slot = 0; slot < 4; ++slot) {
                    unsigned bm = __shfl(m[slot], src);
                    int bj = src * 4 + slot;
                    #pragma unroll
                    for (int s2 = 0; s2 < 4; ++s2) {
                        int myj = lane * 4 + s2;
                        rank[s2] += (bm > m[s2]) || (bm == m[s2] && bj < myj);
                    }
                }
            }
            int j0 = w * 256 + lane * 4;
            #pragma unroll
            for (int s2 = 0; s2 < 4; ++s2)
                if (rank[s2] < U)
                    cnd[w * U + rank[s2]] = ((unsigned long long)m[s2] << 32)
                                          | (unsigned)(~(unsigned)(j0 + s2));
        }
        __syncthreads();

        // merge 320 -> top 40 (packed keys unique => ranks unique)
        if (tid < 8 * U) {
            unsigned long long ka = cnd[tid];
            int ra = 0;
            for (int j = 0; j < 8 * U; ++j) ra += (cnd[j] > ka);
            if (ra < U) {
                int qi = (int)(~(unsigned)ka);
                top_idx[ra] = qi;
                flags[(size_t)bh * L + qi] = ra + 1;
            }
        }
        __syncthreads();

        // stage K[0..39], V[0..39], Q[top_idx[r]] rows (stride 68 floats)
        const float4* V4 = (const float4*)V;
        for (int i2 = tid; i2 < U * 16; i2 += 512) {
            int r = i2 >> 4, d4 = i2 & 15;
            size_t kvb = (size_t)(b * L + r) * 128 + h * 16 + d4;
            *(float4*)(Ks + r * 68 + d4 * 4) = K4[kvb];
            *(float4*)(Vs + r * 68 + d4 * 4) = V4[kvb];
            *(float4*)(Qs + r * 68 + d4 * 4) =
                Q4[(size_t)(b * L + top_idx[r]) * 128 + h * 16 + d4];
        }
        __syncthreads();

        // scores S[r][k], k <= r (causal over rank)
        const float scale = 0.125f;
        for (int p = tid; p < U * U; p += 512) {
            int r = p / U, k = p - r * U;
            if (k <= r) {
                float acc = 0.f;
                #pragma unroll
                for (int d = 0; d < D; d += 4) {
                    float4 a = *(const float4*)(Qs + r * 68 + d);
                    float4 cc = *(const float4*)(Ks + k * 68 + d);
                    acc += a.x * cc.x + a.y * cc.y + a.z * cc.z + a.w * cc.w;
                }
                P[r * 41 + k] = acc * scale;
            }
        }
        __syncthreads();

        if (tid < U) {   // row softmax over k <= r
            int r = tid;
            float mval = -INFINITY;
            for (int k = 0; k <= r; ++k) mval = fmaxf(mval, P[r * 41 + k]);
            float ssum = 0.f;
            for (int k = 0; k <= r; ++k) {
                float e = expf(P[r * 41 + k] - mval);
                P[r * 41 + k] = e;
                ssum += e;
            }
            float inv = 1.f / ssum;
            for (int k = 0; k <= r; ++k) P[r * 41 + k] *= inv;
        }
        __syncthreads();

        for (int t = tid; t < U * D; t += 512) {   // upd = P·V
            int r = t >> 6, d = t & 63;
            float acc = 0.f;
            for (int k = 0; k <= r; ++k) acc += P[r * 41 + k] * Vs[k * 68 + d];
            upd[((size_t)bh * U + r) * D + d] = acc;
        }
    }

    // all blocks: exclusive prefix of chunk sums for own (b, c)
    float acc = 0.f;
    for (int cc = 0; cc < c; ++cc)
        acc += partial[((size_t)b * NC + cc) * HD + tid];

    grid_barrier(slots, bid, 2);

    // ---------------- Phase C: cumsum + scatter epilogue --------------------
    {
        int h = tid >> 6, d = tid & 63;
        const float* vp = V + ((size_t)(b * L + c * CL)) * HD + tid;
        float*       op = out + ((size_t)(b * L + c * CL)) * HD + tid;
        const int*   fp = flags + (size_t)(b * 8 + h) * L + c * CL;
        const float* up = upd + (size_t)(b * 8 + h) * U * D + d;
        #pragma unroll 4
        for (int l = 0; l < CL; ++l) {
            acc += vp[(size_t)l * HD];
            int f = fp[l];
            op[(size_t)l * HD] = f ? up[(size_t)(f - 1) * D] : acc;
        }
    }
}

extern "C" void kernel_launch(void* const* d_in, const int* in_sizes, int n_in,
                              void* d_out, int out_size, void* d_ws, size_t ws_size,
                              hipStream_t stream)
{
    const float* Q   = (const float*)d_in[0];
    const float* K   = (const float*)d_in[1];
    const float* V   = (const float*)d_in[2];
    const int*  idxs = (const int*)d_in[3];
    float* out = (float*)d_out;

    char* ws = (char*)d_ws;
    float* Mg      = (float*)(ws);              // B*H*L floats    = 256 KB
    int*   flags   = (int*)  (ws + 262144);     // B*H*L ints      = 256 KB
    float* upd     = (float*)(ws + 524288);     // B*H*U*D floats  = 320 KB
    float* partial = (float*)(ws + 851968);     // B*NC*HD floats  = 512 KB
    int*   slots   = (int*)  (ws + 1376256);    // 256*64 B        =  16 KB

    k_fused<<<NBLK, 512, 0, stream>>>((const float4*)Q, (const float4*)K, V, idxs,
                                      Mg, flags, upd, partial, slots, out);
}

// Round 5
// 202.855 us; speedup vs baseline: 1.3703x; 1.3703x over previous
//
#include <hip/hip_runtime.h>
#include <stdint.h>

constexpr int B = 4, L = 2048, H = 8, D = 64, S = 40, U = 40;
constexpr int HD = H * D;        // 512
constexpr int NC = 64;           // cumsum chunks per b
constexpr int CL = L / NC;       // 32
constexpr int NBLK = 256;

// monotone float->uint mapping: larger float => larger uint
__device__ __forceinline__ unsigned mono(float v) {
    unsigned u = __float_as_uint(v);
    return (u & 0x80000000u) ? ~u : (u | 0x80000000u);
}

// Cooperative-groups-style grid barrier: ONE device-scope atomicAdd per block
// on a single counter, ONE spinning poller thread per block (agent-scope
// relaxed load + s_sleep backoff). Counters are zeroed by hipMemsetAsync
// before launch. All 256 blocks are co-resident (256 blocks / 256 CUs,
// 8 waves + ~50 KB LDS each), so spinning cannot deadlock.
// __syncthreads drains this block's writes to L2 (vmcnt(0)); thread 0's
// __threadfence does the device-scope L2 writeback (release) / invalidate
// (acquire) for the whole block.
__device__ __forceinline__ void grid_barrier(int* cnt, int idx) {
    __syncthreads();
    if (threadIdx.x == 0) {
        __threadfence();                                    // release
        atomicAdd(&cnt[idx * 32], 1);
        while (__hip_atomic_load(&cnt[idx * 32], __ATOMIC_RELAXED,
                                 __HIP_MEMORY_SCOPE_AGENT) < NBLK)
            __builtin_amdgcn_s_sleep(2);
        __threadfence();                                    // acquire
    }
    __syncthreads();
}

__global__ __launch_bounds__(512) void k_fused(
    const float4* __restrict__ Q4, const float4* __restrict__ K4,
    const float* __restrict__ V, const int* __restrict__ idxs,
    float* __restrict__ Mg, int* __restrict__ flags, float* __restrict__ upd,
    float* __restrict__ partial, int* __restrict__ cnt, float* __restrict__ out)
{
    __shared__ float4 Ms4[512];                    // M row of one bh (2048 floats)
    __shared__ unsigned long long cnd[8 * U];      // 320 candidates
    __shared__ int top_idx[U];
    __shared__ __align__(16) float Qs[U * 68];
    __shared__ __align__(16) float Ks[U * 68];
    __shared__ __align__(16) float Vs[U * 68];
    __shared__ float P[U * 41];

    int bid = blockIdx.x;
    int tid = threadIdx.x;
    // XCD swizzle: blocks land on XCD bid%8; pin each b to an XCD pair so its
    // 4 MB K slab stays L2-resident for the phase-A gather.
    int b   = (bid & 7) >> 1;
    int sub = ((bid >> 3) << 1) | (bid & 1);       // 0..63 within b
    int c   = sub;                                  // this block's cumsum chunk

    // ---------------- Phase A: M scores + V chunk sums + flag zeroing -------
    {
        int w = tid >> 6, lane = tid & 63;
        int dd = lane & 7;
        for (int j = 0; j < 4; ++j) {
            int q = sub * 32 + w * 4 + j;
            const float4* qrow = Q4 + (size_t)(b * L + q) * 128;
            float4 qa = qrow[2 * lane], qb = qrow[2 * lane + 1];
            int v_idx = idxs[q * S + (lane < S ? lane : 0)];
            float mx = -INFINITY, sm = 0.f;
            #pragma unroll 8
            for (int s = 0; s < S; ++s) {
                int ki = __shfl(v_idx, s);
                const float4* krow = K4 + (size_t)(b * L + ki) * 128;
                float4 ka = krow[2 * lane], kb = krow[2 * lane + 1];
                float dt = qa.x * ka.x + qa.y * ka.y + qa.z * ka.z + qa.w * ka.w
                         + qb.x * kb.x + qb.y * kb.y + qb.z * kb.z + qb.w * kb.w;
                dt += __shfl_xor(dt, 1);
                dt += __shfl_xor(dt, 2);
                dt += __shfl_xor(dt, 4);
                mx = fmaxf(mx, dt);
                sm += dt;
            }
            if (dd == 0) {
                int h = lane >> 3;
                Mg[(size_t)(b * 8 + h) * L + q] = mx - sm * (1.0f / (float)L);
            }
        }
    }
    {   // V chunk sum for (b, c)
        const float* vp = V + ((size_t)(b * L + c * CL)) * HD + tid;
        float s = 0.f;
        #pragma unroll
        for (int l = 0; l < CL; ++l) s += vp[(size_t)l * HD];
        partial[((size_t)b * NC + c) * HD + tid] = s;
    }
    if (tid < 256) {   // zero flags for this chunk's rows, all 8 heads
        int h = tid >> 5, l0 = c * CL + (tid & 31);
        flags[(size_t)(b * 8 + h) * L + l0] = 0;
    }

    grid_barrier(cnt, 0);

    // ---------------- Phase B: selection + attention (32 blocks) ------------
    if (sub < 8) {
        int h = sub, bh = b * 8 + h;
        Ms4[tid] = ((const float4*)(Mg + (size_t)bh * L))[tid];
        __syncthreads();

        // per-segment (8 x 256) exact rank counting, one wave per segment
        {
            int w = tid >> 6, lane = tid & 63;
            float4 v = Ms4[w * 64 + lane];
            unsigned m[4] = { mono(v.x), mono(v.y), mono(v.z), mono(v.w) };
            int rank[4] = { 0, 0, 0, 0 };
            #pragma unroll 4
            for (int src = 0; src < 64; ++src) {
                #pragma unroll
                for (int slot = 0; slot < 4; ++slot) {
                    unsigned bm = __shfl(m[slot], src);
                    int bj = src * 4 + slot;
                    #pragma unroll
                    for (int s2 = 0; s2 < 4; ++s2) {
                        int myj = lane * 4 + s2;
                        rank[s2] += (bm > m[s2]) || (bm == m[s2] && bj < myj);
                    }
                }
            }
            int j0 = w * 256 + lane * 4;
            #pragma unroll
            for (int s2 = 0; s2 < 4; ++s2)
                if (rank[s2] < U)
                    cnd[w * U + rank[s2]] = ((unsigned long long)m[s2] << 32)
                                          | (unsigned)(~(unsigned)(j0 + s2));
        }
        __syncthreads();

        // merge 320 -> top 40 (packed keys unique => ranks unique)
        if (tid < 8 * U) {
            unsigned long long ka = cnd[tid];
            int ra = 0;
            for (int j = 0; j < 8 * U; ++j) ra += (cnd[j] > ka);
            if (ra < U) {
                int qi = (int)(~(unsigned)ka);
                top_idx[ra] = qi;
                flags[(size_t)bh * L + qi] = ra + 1;
            }
        }
        __syncthreads();

        // stage K[0..39], V[0..39], Q[top_idx[r]] rows (stride 68 floats)
        const float4* V4 = (const float4*)V;
        for (int i2 = tid; i2 < U * 16; i2 += 512) {
            int r = i2 >> 4, d4 = i2 & 15;
            size_t kvb = (size_t)(b * L + r) * 128 + h * 16 + d4;
            *(float4*)(Ks + r * 68 + d4 * 4) = K4[kvb];
            *(float4*)(Vs + r * 68 + d4 * 4) = V4[kvb];
            *(float4*)(Qs + r * 68 + d4 * 4) =
                Q4[(size_t)(b * L + top_idx[r]) * 128 + h * 16 + d4];
        }
        __syncthreads();

        // scores S[r][k], k <= r (causal over rank)
        const float scale = 0.125f;
        for (int p = tid; p < U * U; p += 512) {
            int r = p / U, k = p - r * U;
            if (k <= r) {
                float acc = 0.f;
                #pragma unroll
                for (int d = 0; d < D; d += 4) {
                    float4 a = *(const float4*)(Qs + r * 68 + d);
                    float4 cc = *(const float4*)(Ks + k * 68 + d);
                    acc += a.x * cc.x + a.y * cc.y + a.z * cc.z + a.w * cc.w;
                }
                P[r * 41 + k] = acc * scale;
            }
        }
        __syncthreads();

        if (tid < U) {   // row softmax over k <= r
            int r = tid;
            float mval = -INFINITY;
            for (int k = 0; k <= r; ++k) mval = fmaxf(mval, P[r * 41 + k]);
            float ssum = 0.f;
            for (int k = 0; k <= r; ++k) {
                float e = expf(P[r * 41 + k] - mval);
                P[r * 41 + k] = e;
                ssum += e;
            }
            float inv = 1.f / ssum;
            for (int k = 0; k <= r; ++k) P[r * 41 + k] *= inv;
        }
        __syncthreads();

        for (int t = tid; t < U * D; t += 512) {   // upd = P·V
            int r = t >> 6, d = t & 63;
            float acc = 0.f;
            for (int k = 0; k <= r; ++k) acc += P[r * 41 + k] * Vs[k * 68 + d];
            upd[((size_t)bh * U + r) * D + d] = acc;
        }
    }

    // all blocks: exclusive prefix of chunk sums for own (b, c)
    float acc = 0.f;
    for (int cc = 0; cc < c; ++cc)
        acc += partial[((size_t)b * NC + cc) * HD + tid];

    grid_barrier(cnt, 1);

    // ---------------- Phase C: cumsum + scatter epilogue --------------------
    {
        int h = tid >> 6, d = tid & 63;
        const float* vp = V + ((size_t)(b * L + c * CL)) * HD + tid;
        float*       op = out + ((size_t)(b * L + c * CL)) * HD + tid;
        const int*   fp = flags + (size_t)(b * 8 + h) * L + c * CL;
        const float* up = upd + (size_t)(b * 8 + h) * U * D + d;
        #pragma unroll 4
        for (int l = 0; l < CL; ++l) {
            acc += vp[(size_t)l * HD];
            int f = fp[l];
            op[(size_t)l * HD] = f ? up[(size_t)(f - 1) * D] : acc;
        }
    }
}

extern "C" void kernel_launch(void* const* d_in, const int* in_sizes, int n_in,
                              void* d_out, int out_size, void* d_ws, size_t ws_size,
                              hipStream_t stream)
{
    const float* Q   = (const float*)d_in[0];
    const float* K   = (const float*)d_in[1];
    const float* V   = (const float*)d_in[2];
    const int*  idxs = (const int*)d_in[3];
    float* out = (float*)d_out;

    char* ws = (char*)d_ws;
    float* Mg      = (float*)(ws);              // B*H*L floats    = 256 KB
    int*   flags   = (int*)  (ws + 262144);     // B*H*L ints      = 256 KB
    float* upd     = (float*)(ws + 524288);     // B*H*U*D floats  = 320 KB
    float* partial = (float*)(ws + 851968);     // B*NC*HD floats  = 512 KB
    int*   cnt     = (int*)  (ws + 1376256);    // barrier counters (256 B)

    hipMemsetAsync(cnt, 0, 256, stream);        // zero barrier counters (capture-legal)
    k_fused<<<NBLK, 512, 0, stream>>>((const float4*)Q, (const float4*)K, V, idxs,
                                      Mg, flags, upd, partial, cnt, out);
}

// Round 6
// 192.835 us; speedup vs baseline: 1.4415x; 1.0520x over previous
//
#include <hip/hip_runtime.h>
#include <stdint.h>

constexpr int B = 4, L = 2048, H = 8, D = 64, S = 40, U = 40;
constexpr int HD = H * D;        // 512
constexpr int NC = 64;           // cumsum chunks per b
constexpr int CL = L / NC;       // 32
constexpr int NBLK = 256;

// monotone float->uint mapping: larger float => larger uint
__device__ __forceinline__ unsigned mono(float v) {
    unsigned u = __float_as_uint(v);
    return (u & 0x80000000u) ? ~u : (u | 0x80000000u);
}

// Grid barrier: one device-scope atomicAdd per block on a single counter,
// one polling thread per block (agent-scope relaxed load + s_sleep).
// cnt[] zeroed by hipMemsetAsync pre-launch. 256 blocks on 256 CUs
// (16 waves + ~50 KB LDS each) => all co-resident, no deadlock.
__device__ __forceinline__ void grid_barrier(int* cnt, int idx) {
    __syncthreads();
    if (threadIdx.x == 0) {
        __threadfence();                                    // release
        atomicAdd(&cnt[idx * 32], 1);
        while (__hip_atomic_load(&cnt[idx * 32], __ATOMIC_RELAXED,
                                 __HIP_MEMORY_SCOPE_AGENT) < NBLK)
            __builtin_amdgcn_s_sleep(2);
        __threadfence();                                    // acquire
    }
    __syncthreads();
}

__device__ __forceinline__ float dot8(float4 a, float4 b, float4 c, float4 d) {
    return a.x * c.x + a.y * c.y + a.z * c.z + a.w * c.w
         + b.x * d.x + b.y * d.y + b.z * d.z + b.w * d.w;
}

__global__ __launch_bounds__(1024, 4) void k_fused(
    const float4* __restrict__ Q4, const float4* __restrict__ K4,
    const float* __restrict__ V, const int* __restrict__ idxs,
    float* __restrict__ Mg, int* __restrict__ flags, float* __restrict__ upd,
    float* __restrict__ partial2, int* __restrict__ cnt, float* __restrict__ out)
{
    __shared__ float4 Ms4[512];                    // M row of one bh (2048 floats)
    __shared__ unsigned long long cnd[8 * U];      // 320 candidates
    __shared__ int top_idx[U];
    __shared__ __align__(16) float Qs[U * 68];
    __shared__ __align__(16) float Ks[U * 68];
    __shared__ __align__(16) float Vs[U * 68];
    __shared__ float P[U * 41];

    int bid = blockIdx.x;
    int tid = threadIdx.x;
    // XCD swizzle: blocks land on XCD bid%8; pin each b to an XCD pair so its
    // 4 MB K slab stays L2-resident for the phase-A gather.
    int b   = (bid & 7) >> 1;
    int sub = ((bid >> 3) << 1) | (bid & 1);       // 0..63 within b
    int c   = sub;                                  // this block's cumsum chunk

    // ------- Phase A: M scores (2 queries per wave, interleaved ILP) --------
    {
        int w = tid >> 6, lane = tid & 63;          // w: 0..15
        int dd = lane & 7;
        int q0 = sub * 32 + w * 2;
        const float4* qrow0 = Q4 + (size_t)(b * L + q0) * 128;
        const float4* qrow1 = qrow0 + 128;
        float4 qa0 = qrow0[2 * lane], qb0 = qrow0[2 * lane + 1];
        float4 qa1 = qrow1[2 * lane], qb1 = qrow1[2 * lane + 1];
        int li = (lane < S ? lane : 0);
        int vi0 = idxs[q0 * S + li];
        int vi1 = idxs[(q0 + 1) * S + li];
        const float4* kbase = K4 + (size_t)b * L * 128;
        float mx0 = -INFINITY, sm0 = 0.f, mx1 = -INFINITY, sm1 = 0.f;
        #pragma unroll 4
        for (int s = 0; s < S; ++s) {
            const float4* kr0 = kbase + (size_t)__shfl(vi0, s) * 128;
            const float4* kr1 = kbase + (size_t)__shfl(vi1, s) * 128;
            float4 ka0 = kr0[2 * lane], kb0 = kr0[2 * lane + 1];
            float4 ka1 = kr1[2 * lane], kb1 = kr1[2 * lane + 1];
            float d0 = dot8(qa0, qb0, ka0, kb0);
            float d1 = dot8(qa1, qb1, ka1, kb1);
            d0 += __shfl_xor(d0, 1);
            d1 += __shfl_xor(d1, 1);
            d0 += __shfl_xor(d0, 2);
            d1 += __shfl_xor(d1, 2);
            d0 += __shfl_xor(d0, 4);
            d1 += __shfl_xor(d1, 4);
            mx0 = fmaxf(mx0, d0);  sm0 += d0;
            mx1 = fmaxf(mx1, d1);  sm1 += d1;
        }
        if (dd == 0) {
            int h = lane >> 3;
            float* mrow = Mg + (size_t)(b * 8 + h) * L + q0;
            mrow[0] = mx0 - sm0 * (1.0f / (float)L);
            mrow[1] = mx1 - sm1 * (1.0f / (float)L);
        }
    }
    {   // V half-chunk sums: half = tid>>9 covers rows half*16..+15 of chunk c
        int half = tid >> 9, col = tid & 511;
        const float* vp = V + ((size_t)(b * L + c * CL + half * 16)) * HD + col;
        float s = 0.f;
        #pragma unroll
        for (int l = 0; l < 16; ++l) s += vp[(size_t)l * HD];
        partial2[(((size_t)b * NC + c) * 2 + half) * HD + col] = s;
    }
    if (tid < 256) {   // zero flags for this chunk's rows, all 8 heads
        int h = tid >> 5, l0 = c * CL + (tid & 31);
        flags[(size_t)(b * 8 + h) * L + l0] = 0;
    }

    grid_barrier(cnt, 0);

    // ---------------- Phase B: selection + attention (32 blocks) ------------
    if (sub < 8) {
        int h = sub, bh = b * 8 + h;
        if (tid < 512) Ms4[tid] = ((const float4*)(Mg + (size_t)bh * L))[tid];
        __syncthreads();

        // per-segment (8 x 256) exact rank counting, one wave per segment
        if (tid < 512) {
            int w = tid >> 6, lane = tid & 63;
            float4 v = Ms4[w * 64 + lane];
            unsigned m[4] = { mono(v.x), mono(v.y), mono(v.z), mono(v.w) };
            int rank[4] = { 0, 0, 0, 0 };
            #pragma unroll 4
            for (int src = 0; src < 64; ++src) {
                #pragma unroll
                for (int slot = 0; slot < 4; ++slot) {
                    unsigned bm = __shfl(m[slot], src);
                    int bj = src * 4 + slot;
                    #pragma unroll
                    for (int s2 = 0; s2 < 4; ++s2) {
                        int myj = lane * 4 + s2;
                        rank[s2] += (bm > m[s2]) || (bm == m[s2] && bj < myj);
                    }
                }
            }
            int j0 = w * 256 + lane * 4;
            #pragma unroll
            for (int s2 = 0; s2 < 4; ++s2)
                if (rank[s2] < U)
                    cnd[w * U + rank[s2]] = ((unsigned long long)m[s2] << 32)
                                          | (unsigned)(~(unsigned)(j0 + s2));
        }
        __syncthreads();

        // merge 320 -> top 40 (packed keys unique => ranks unique)
        if (tid < 8 * U) {
            unsigned long long ka = cnd[tid];
            int ra = 0;
            for (int j = 0; j < 8 * U; ++j) ra += (cnd[j] > ka);
            if (ra < U) {
                int qi = (int)(~(unsigned)ka);
                top_idx[ra] = qi;
                flags[(size_t)bh * L + qi] = ra + 1;
            }
        }
        __syncthreads();

        // stage K[0..39], V[0..39], Q[top_idx[r]] rows (stride 68 floats)
        const float4* V4 = (const float4*)V;
        if (tid < U * 16) {
            int r = tid >> 4, d4 = tid & 15;
            size_t kvb = (size_t)(b * L + r) * 128 + h * 16 + d4;
            *(float4*)(Ks + r * 68 + d4 * 4) = K4[kvb];
            *(float4*)(Vs + r * 68 + d4 * 4) = V4[kvb];
            *(float4*)(Qs + r * 68 + d4 * 4) =
                Q4[(size_t)(b * L + top_idx[r]) * 128 + h * 16 + d4];
        }
        __syncthreads();

        // scores S[r][k], k <= r (causal over rank)
        const float scale = 0.125f;
        for (int p = tid; p < U * U; p += 1024) {
            int r = p / U, k = p - r * U;
            if (k <= r) {
                float acc = 0.f;
                #pragma unroll
                for (int d = 0; d < D; d += 4) {
                    float4 a = *(const float4*)(Qs + r * 68 + d);
                    float4 cc = *(const float4*)(Ks + k * 68 + d);
                    acc += a.x * cc.x + a.y * cc.y + a.z * cc.z + a.w * cc.w;
                }
                P[r * 41 + k] = acc * scale;
            }
        }
        __syncthreads();

        if (tid < U) {   // row softmax over k <= r
            int r = tid;
            float mval = -INFINITY;
            for (int k = 0; k <= r; ++k) mval = fmaxf(mval, P[r * 41 + k]);
            float ssum = 0.f;
            for (int k = 0; k <= r; ++k) {
                float e = expf(P[r * 41 + k] - mval);
                P[r * 41 + k] = e;
                ssum += e;
            }
            float inv = 1.f / ssum;
            for (int k = 0; k <= r; ++k) P[r * 41 + k] *= inv;
        }
        __syncthreads();

        for (int t = tid; t < U * D; t += 1024) {   // upd = P·V
            int r = t >> 6, d = t & 63;
            float acc = 0.f;
            for (int k = 0; k <= r; ++k) acc += P[r * 41 + k] * Vs[k * 68 + d];
            upd[((size_t)bh * U + r) * D + d] = acc;
        }
    }

    // all blocks: exclusive prefix over half-chunk sums for own (b, c, half)
    float acc = 0.f;
    {
        int half = tid >> 9, col = tid & 511;
        int key = c * 2 + half;
        const float* pp = partial2 + (size_t)b * NC * 2 * HD + col;
        #pragma unroll 4
        for (int j = 0; j < key; ++j)
            acc += pp[(size_t)j * HD];
    }

    grid_barrier(cnt, 1);

    // ---------------- Phase C: cumsum + scatter epilogue --------------------
    {
        int half = tid >> 9, col = tid & 511;
        int h = col >> 6, d = col & 63;
        int r0 = c * CL + half * 16;
        const float* vp = V + ((size_t)(b * L + r0)) * HD + col;
        float*       op = out + ((size_t)(b * L + r0)) * HD + col;
        const int*   fp = flags + (size_t)(b * 8 + h) * L + r0;
        const float* up = upd + (size_t)(b * 8 + h) * U * D + d;
        #pragma unroll 4
        for (int l = 0; l < 16; ++l) {
            acc += vp[(size_t)l * HD];
            int f = fp[l];
            op[(size_t)l * HD] = f ? up[(size_t)(f - 1) * D] : acc;
        }
    }
}

extern "C" void kernel_launch(void* const* d_in, const int* in_sizes, int n_in,
                              void* d_out, int out_size, void* d_ws, size_t ws_size,
                              hipStream_t stream)
{
    const float* Q   = (const float*)d_in[0];
    const float* K   = (const float*)d_in[1];
    const float* V   = (const float*)d_in[2];
    const int*  idxs = (const int*)d_in[3];
    float* out = (float*)d_out;

    char* ws = (char*)d_ws;
    float* Mg       = (float*)(ws);              // B*H*L floats       = 256 KB
    int*   flags    = (int*)  (ws + 262144);     // B*H*L ints         = 256 KB
    float* upd      = (float*)(ws + 524288);     // B*H*U*D floats     = 320 KB
    float* partial2 = (float*)(ws + 851968);     // B*NC*2*HD floats   = 1 MB
    int*   cnt      = (int*)  (ws + 1900544);    // barrier counters (256 B)

    hipMemsetAsync(cnt, 0, 256, stream);         // zero barrier counters
    k_fused<<<NBLK, 1024, 0, stream>>>((const float4*)Q, (const float4*)K, V, idxs,
                                       Mg, flags, upd, partial2, cnt, out);
}